// Round 17
// baseline (619.271 us; speedup 1.0000x reference)
//
#include <hip/hip_runtime.h>

typedef unsigned short ushort;
using short8 = __attribute__((ext_vector_type(8))) short;
using f32x4  = __attribute__((ext_vector_type(4))) float;
using i32x4  = __attribute__((ext_vector_type(4))) int;
using us4    = __attribute__((ext_vector_type(4))) ushort;

static __device__ __forceinline__ float bf2f(ushort u) {
  union { unsigned int i; float f; } x; x.i = ((unsigned int)u) << 16; return x.f;
}
static __device__ __forceinline__ ushort f2bf(float f) {
  union { float f; unsigned int i; } x; x.f = f;
  unsigned int u = x.i;
  unsigned int r = u + 0x7fffu + ((u >> 16) & 1u);
  return (ushort)(r >> 16);
}

// async global -> LDS, 16B per lane; LDS dest is wave-uniform base + lane*16
#define GLOAD16(gp, lp)                                                   \
  __builtin_amdgcn_global_load_lds(                                      \
      (const __attribute__((address_space(1))) void*)(gp),               \
      (__attribute__((address_space(3))) void*)(lp), 16, 0, 0)

// ---------------- weight prep ----------------
__global__ __launch_bounds__(256) void wtrans_kernel(const float* __restrict__ in,
                                                     ushort* __restrict__ out,
                                                     int R, int C) {
  __shared__ float sl[32][33];
  int tx = threadIdx.x & 31, ty = threadIdx.x >> 5;
  int c0 = blockIdx.x * 32, r0 = blockIdx.y * 32;
#pragma unroll
  for (int s = 0; s < 4; s++) {
    int r = r0 + ty + s * 8;
    int c = c0 + tx;
    sl[ty + s * 8][tx] = (c < C) ? in[(size_t)r * C + c] : 0.f;
  }
  __syncthreads();
#pragma unroll
  for (int s = 0; s < 4; s++) {
    int c = c0 + ty + s * 8;
    int r = r0 + tx;
    out[(size_t)c * R + r] = f2bf(sl[tx][ty + s * 8]);
  }
}

__global__ void wsplit_kernel(const float* __restrict__ in, ushort* __restrict__ hi,
                              ushort* __restrict__ lo, int n) {
  int i = blockIdx.x * 256 + threadIdx.x;
  if (i < n) {
    float v = in[i];
    ushort h = f2bf(v);
    hi[i] = h;
    lo[i] = f2bf(v - bf2f(h));
  }
}

// ---------------- fused LayerNorm (R14-verified 32-t slab) ----------------
__global__ __launch_bounds__(512) void ln_fused_kernel(const float* __restrict__ x,
                                                       const float* __restrict__ g,
                                                       const float* __restrict__ b,
                                                       ushort* __restrict__ xn) {
  __shared__ float sl[960][34];
  __shared__ float smean[32], srstd[32];
  int tid = threadIdx.x;
  int nm = blockIdx.y;
  int t0 = blockIdx.x * 32;

  int r0 = tid >> 3, c4 = (tid & 7) * 4;
#pragma unroll
  for (int it = 0; it < 15; it++) {
    int r = it * 64 + r0;
    float4 v = *(const float4*)&x[((size_t)nm * 960 + r) * 256 + t0 + c4];
    *(float4*)&sl[r][c4] = v;
  }
  __syncthreads();

  int tg = tid >> 4, lt = tid & 15;
  float s = 0.f, ss = 0.f;
#pragma unroll 4
  for (int k = 0; k < 60; k++) {
    float v = sl[lt + k * 16][tg];
    s += v; ss += v * v;
  }
#pragma unroll
  for (int d = 1; d < 16; d <<= 1) {
    s += __shfl_xor(s, d, 64);
    ss += __shfl_xor(ss, d, 64);
  }
  if (lt == 0) {
    float mean = s * (1.f / 960.f);
    float var = ss * (1.f / 960.f) - mean * mean;
    smean[tg] = mean;
    srstd[tg] = rsqrtf(var + 1e-5f);
  }
  __syncthreads();

  float gg[2], bb[2];
#pragma unroll
  for (int c = 0; c < 2; c++) {
    int col = c * 512 + tid;
    if (col < 960) { gg[c] = g[col]; bb[c] = b[col]; }
  }
#pragma unroll
  for (int t = 0; t < 32; t++) {
    float mean = smean[t], rstd = srstd[t];
#pragma unroll
    for (int c = 0; c < 2; c++) {
      int col = c * 512 + tid;
      if (col < 960)
        xn[((size_t)nm * 256 + t0 + t) * 960 + col] =
            f2bf((sl[col][t] - mean) * rstd * gg[c] + bb[c]);
    }
  }
}

// ---------------- 256x256 GEMM, BK=64, 8 waves, counted-vmcnt pipeline (R9 anchor) ----
// LDS 128KB. Regions (16KB each, [256 rows][32 cols]): A(d,kk) @ d*32768+kk*16384,
// B(d,kk) @ 65536 + same. 16B-slot s stored at s ^ ((row>>1)&3) [verified 0-conflict].
// MODE 0: QKV epilogue.
// MODE 1: proj + b_out -> LDS bf16 tile -> coalesced residual(x) + hi/lo split.
// MODE 2: 3-seg split-bf16 + tanh -> f32 out.
template <int MODE>
__global__ __launch_bounds__(512, 2) void gemm256(
    const ushort* __restrict__ A, int lda, const ushort* __restrict__ BT, int ldb, int nkt,
    const ushort* __restrict__ Alo, const ushort* __restrict__ Blo,
    ushort* __restrict__ o0, ushort* __restrict__ o1, ushort* __restrict__ o2,
    const float* __restrict__ bias, const float* __restrict__ xres,
    float* __restrict__ fout) {
  __shared__ char smem[131072];
  int tid = threadIdx.x;
  int l = tid & 63, w = tid >> 6;
  int wr = w >> 2, wc = w & 3;
  int lr = l & 15, lg = l >> 4;
  int cb = blockIdx.x * 256, rb = blockIdx.y * 256;

  int srow = tid >> 2;
  int scol = ((tid & 3) ^ ((tid >> 3) & 3)) * 8;

  int swz = (lg ^ ((lr >> 1) & 3)) << 4;
  const char* ArdB = smem + (wr * 128 + lr) * 64 + swz;
  const char* BrdB = smem + 65536 + (wc * 64 + lr) * 64 + swz;

  auto stage_half = [&](int kt, int kk, int isB) {
    const ushort* P; int ld; int k0;
    if (MODE == 2) {
      int seg = kt >> 2; k0 = (kt & 3) * 64 + kk * 32;
      P = isB ? ((seg == 1) ? Blo : BT) : ((seg == 2) ? Alo : A);
      ld = 256;
    } else {
      P = isB ? BT : A; ld = isB ? ldb : lda; k0 = kt * 64 + kk * 32;
    }
    const ushort* gp = P + (size_t)((isB ? cb : rb) + srow) * ld + k0 + scol;
    char* dst = smem + isB * 65536 + (kt & 1) * 32768 + kk * 16384 + tid * 16;
    GLOAD16(gp, dst);
    GLOAD16(gp + (size_t)128 * ld, dst + 8192);
  };

  f32x4 acc[8][4];
#pragma unroll
  for (int i = 0; i < 8; i++)
#pragma unroll
    for (int j = 0; j < 4; j++) acc[i][j] = (f32x4){0.f, 0.f, 0.f, 0.f};

  stage_half(0, 0, 0); stage_half(0, 0, 1); stage_half(0, 1, 0); stage_half(0, 1, 1);
  asm volatile("s_waitcnt vmcnt(4)" ::: "memory");
  __builtin_amdgcn_s_barrier();

  for (int t = 0; t < nkt; t++) {
    const char* Ard = ArdB + (t & 1) * 32768;
    const char* Brd = BrdB + (t & 1) * 32768;
    bool st = (t + 1 < nkt);
    short8 a[4], b[4];

#pragma unroll
    for (int j = 0; j < 4; j++) b[j] = *(const short8*)(Brd + j * 1024);
#pragma unroll
    for (int i = 0; i < 4; i++) a[i] = *(const short8*)(Ard + i * 1024);
    if (st) stage_half(t + 1, 0, 0);
    __builtin_amdgcn_s_barrier();
    __builtin_amdgcn_s_setprio(1);
#pragma unroll
    for (int i = 0; i < 4; i++)
#pragma unroll
      for (int j = 0; j < 4; j++)
        acc[i][j] = __builtin_amdgcn_mfma_f32_16x16x32_bf16(a[i], b[j], acc[i][j], 0, 0, 0);
    __builtin_amdgcn_s_setprio(0);
    __builtin_amdgcn_s_barrier();

#pragma unroll
    for (int i = 0; i < 4; i++) a[i] = *(const short8*)(Ard + (4 + i) * 1024);
    if (st) stage_half(t + 1, 0, 1);
    __builtin_amdgcn_s_barrier();
    __builtin_amdgcn_s_setprio(1);
#pragma unroll
    for (int i = 0; i < 4; i++)
#pragma unroll
      for (int j = 0; j < 4; j++)
        acc[4 + i][j] = __builtin_amdgcn_mfma_f32_16x16x32_bf16(a[i], b[j], acc[4 + i][j], 0, 0, 0);
    __builtin_amdgcn_s_setprio(0);
    if (st) asm volatile("s_waitcnt vmcnt(4)" ::: "memory");
    else    asm volatile("s_waitcnt vmcnt(0)" ::: "memory");
    __builtin_amdgcn_s_barrier();

#pragma unroll
    for (int j = 0; j < 4; j++) b[j] = *(const short8*)(Brd + 16384 + j * 1024);
#pragma unroll
    for (int i = 0; i < 4; i++) a[i] = *(const short8*)(Ard + 16384 + i * 1024);
    if (st) stage_half(t + 1, 1, 0);
    __builtin_amdgcn_s_barrier();
    __builtin_amdgcn_s_setprio(1);
#pragma unroll
    for (int i = 0; i < 4; i++)
#pragma unroll
      for (int j = 0; j < 4; j++)
        acc[i][j] = __builtin_amdgcn_mfma_f32_16x16x32_bf16(a[i], b[j], acc[i][j], 0, 0, 0);
    __builtin_amdgcn_s_setprio(0);
    __builtin_amdgcn_s_barrier();

#pragma unroll
    for (int i = 0; i < 4; i++) a[i] = *(const short8*)(Ard + 16384 + (4 + i) * 1024);
    if (st) stage_half(t + 1, 1, 1);
    __builtin_amdgcn_s_barrier();
    __builtin_amdgcn_s_setprio(1);
#pragma unroll
    for (int i = 0; i < 4; i++)
#pragma unroll
      for (int j = 0; j < 4; j++)
        acc[4 + i][j] = __builtin_amdgcn_mfma_f32_16x16x32_bf16(a[i], b[j], acc[4 + i][j], 0, 0, 0);
    __builtin_amdgcn_s_setprio(0);
    if (st) asm volatile("s_waitcnt vmcnt(4)" ::: "memory");
    else    asm volatile("s_waitcnt vmcnt(0)" ::: "memory");
    __builtin_amdgcn_s_barrier();
  }

  int row0 = rb + wr * 128, col0 = cb + wc * 64;
  if (MODE == 0) {
    int nm = rb >> 8;
    int which = cb >> 10;
#pragma unroll
    for (int i = 0; i < 8; i++)
#pragma unroll
      for (int j = 0; j < 4; j++) {
        f32x4 v = acc[i][j];
        int col = col0 + j * 16 + lr;
        int cl = col & 1023;
        int h = cl >> 7, d = cl & 127;
        int nmh = nm * 8 + h;
        int t0 = wr * 128 + i * 16 + lg * 4;
        if (which == 2) {
          us4 pk;
          pk.x = f2bf(v[0]); pk.y = f2bf(v[1]); pk.z = f2bf(v[2]); pk.w = f2bf(v[3]);
          *(us4*)&o2[((size_t)nmh * 128 + d) * 256 + t0] = pk;  // V^T, 8B packed
        } else if (which == 0) {
#pragma unroll
          for (int r = 0; r < 4; r++)
            o0[((size_t)nmh * 256 + t0 + r) * 128 + d] = f2bf(v[r] * 0.08838834764831845f);
        } else {
#pragma unroll
          for (int r = 0; r < 4; r++)
            o1[((size_t)nmh * 256 + t0 + r) * 128 + d] = f2bf(v[r]);
        }
      }
  } else if (MODE == 1) {
    // stash proj+bias (bf16) into LDS [cv_local][t], swizzled slot (t*2)^((cv&15)<<3)
    int nm = rb >> 8;
#pragma unroll
    for (int i = 0; i < 8; i++)
#pragma unroll
      for (int j = 0; j < 4; j++) {
        f32x4 v = acc[i][j];
        int cvl = wc * 64 + j * 16 + lr;
        int col = cb + cvl;
        float bb = (col < 960) ? bias[col] : 0.f;
        int t0 = wr * 128 + i * 16 + lg * 4;
        us4 pk;
        pk.x = f2bf(v[0] + bb); pk.y = f2bf(v[1] + bb);
        pk.z = f2bf(v[2] + bb); pk.w = f2bf(v[3] + bb);
        *(us4*)(smem + cvl * 512 + ((t0 * 2) ^ ((cvl & 15) << 3))) = pk;
      }
    __syncthreads();
    // coalesced pass: wave w covers cv rows {it*8+w}; lane l covers t=4l..4l+3
    for (int it = 0; it < 32; it++) {
      int cvl = it * 8 + w;
      int col = cb + cvl;
      if (col < 960) {
        us4 pv = *(const us4*)(smem + cvl * 512 + ((l * 8) ^ ((cvl & 15) << 3)));
        size_t base = ((size_t)nm * 960 + col) * 256 + l * 4;
        f32x4 xv = *(const f32x4*)&xres[base];
        us4 h4, l4;
#pragma unroll
        for (int e = 0; e < 4; e++) {
          float s = xv[e] + bf2f(pv[e]);
          ushort hh = f2bf(s);
          h4[e] = hh;
          l4[e] = f2bf(s - bf2f(hh));
        }
        *(us4*)&o0[base] = h4;
        *(us4*)&o1[base] = l4;
      }
    }
  } else {
#pragma unroll
    for (int i = 0; i < 8; i++)
#pragma unroll
      for (int j = 0; j < 4; j++) {
        f32x4 v = acc[i][j];
        int col = col0 + j * 16 + lr;
        float bb = bias[col];
#pragma unroll
        for (int r = 0; r < 4; r++) {
          int row = row0 + i * 16 + lg * 4 + r;
          fout[(size_t)row * 256 + col] = tanhf(v[r] + bb);
        }
      }
  }
}

// ---------------- attention v3: K staged in LDS; V read direct from global ----------------
// V-destaging (m169 pattern): per-block V is 64KB with 8x intra-block reuse that L1/L2
// serves; staging it cost occupancy (128KB LDS -> 1 block/CU). Now smem=64KB -> 2
// blocks/CU; staging/softmax of one block overlaps MFMA of the other. P-chunks still
// overlay the dead K region after the post-QK^T barrier.
__global__ __launch_bounds__(512, 2) void attn2_kernel(const ushort* __restrict__ q,
                                                       const ushort* __restrict__ kb,
                                                       const ushort* __restrict__ vT,
                                                       ushort* __restrict__ ao) {
  __shared__ char smem[65536];
  int tid = threadIdx.x;
  int l = tid & 63, w = tid >> 6;
  int lr = l & 15, lg = l >> 4;
  int nmh = blockIdx.x;

  const ushort* kbase = kb + (size_t)nmh * 32768;
  const ushort* vbase = vT + (size_t)nmh * 32768;

  // stage K (8 x gload16): source pre-swizzled, LDS linear (verified since R5)
#pragma unroll
  for (int u = 0; u < 8; u++) {
    int row = u * 32 + w * 4 + (l >> 4);
    int slot = l & 15;
    GLOAD16(kbase + row * 128 + ((slot ^ (row & 7)) * 8), smem + u * 8192 + w * 1024);
  }
  // q fragments (8 x 16B global loads)
  short8 aq[2][4];
  {
    const ushort* qp = q + (size_t)nmh * 32768 + (size_t)(w * 32 + lr) * 128 + lg * 8;
#pragma unroll
    for (int i = 0; i < 2; i++)
#pragma unroll
      for (int kk = 0; kk < 4; kk++) aq[i][kk] = *(const short8*)(qp + i * 2048 + kk * 32);
  }
  asm volatile("s_waitcnt vmcnt(0)" ::: "memory");
  __builtin_amdgcn_s_barrier();

  f32x4 s_acc[2][16];
#pragma unroll
  for (int i = 0; i < 2; i++)
#pragma unroll
    for (int j = 0; j < 16; j++) s_acc[i][j] = (f32x4){0.f, 0.f, 0.f, 0.f};
#pragma unroll
  for (int j = 0; j < 16; j++) {
    short8 bk[4];
#pragma unroll
    for (int kk = 0; kk < 4; kk++)
      bk[kk] = *(const short8*)(smem + (j * 16 + lr) * 256 + (((kk * 4 + lg) ^ (lr & 7)) << 4));
#pragma unroll
    for (int i = 0; i < 2; i++)
#pragma unroll
      for (int kk = 0; kk < 4; kk++)
        s_acc[i][j] = __builtin_amdgcn_mfma_f32_16x16x32_bf16(aq[i][kk], bk[kk], s_acc[i][j], 0, 0, 0);
  }

  float m[2][4], sum[2][4], rs[2][4];
#pragma unroll
  for (int i = 0; i < 2; i++)
#pragma unroll
    for (int r = 0; r < 4; r++) m[i][r] = -1e30f;
#pragma unroll
  for (int i = 0; i < 2; i++)
#pragma unroll
    for (int j = 0; j < 16; j++)
#pragma unroll
      for (int r = 0; r < 4; r++) m[i][r] = fmaxf(m[i][r], s_acc[i][j][r]);
#pragma unroll
  for (int d = 1; d < 16; d <<= 1)
#pragma unroll
    for (int i = 0; i < 2; i++)
#pragma unroll
      for (int r = 0; r < 4; r++) m[i][r] = fmaxf(m[i][r], __shfl_xor(m[i][r], d, 64));
#pragma unroll
  for (int i = 0; i < 2; i++)
#pragma unroll
    for (int r = 0; r < 4; r++) sum[i][r] = 0.f;
#pragma unroll
  for (int i = 0; i < 2; i++)
#pragma unroll
    for (int j = 0; j < 16; j++)
#pragma unroll
      for (int r = 0; r < 4; r++) {
        float p = __expf(s_acc[i][j][r] - m[i][r]);
        s_acc[i][j][r] = p;
        sum[i][r] += p;
      }
#pragma unroll
  for (int d = 1; d < 16; d <<= 1)
#pragma unroll
    for (int i = 0; i < 2; i++)
#pragma unroll
      for (int r = 0; r < 4; r++) sum[i][r] += __shfl_xor(sum[i][r], d, 64);
#pragma unroll
  for (int i = 0; i < 2; i++)
#pragma unroll
    for (int r = 0; r < 4; r++) rs[i][r] = 1.f / sum[i][r];

  __builtin_amdgcn_s_barrier();   // all waves done reading K region; P-chunks may overwrite

  char* Pb = smem + w * 4608;
  f32x4 o_acc[2][8];
#pragma unroll
  for (int i = 0; i < 2; i++)
#pragma unroll
    for (int j = 0; j < 8; j++) o_acc[i][j] = (f32x4){0.f, 0.f, 0.f, 0.f};

#pragma unroll
  for (int ct = 0; ct < 4; ct++) {
#pragma unroll
    for (int i = 0; i < 2; i++)
#pragma unroll
      for (int jj = 0; jj < 4; jj++)
#pragma unroll
        for (int r = 0; r < 4; r++)
          *(ushort*)(Pb + (i * 16 + lg * 4 + r) * 144 + (jj * 16 + lr) * 2) =
              f2bf(s_acc[i][ct * 4 + jj][r]);
    short8 pa[2][2];
#pragma unroll
    for (int i = 0; i < 2; i++)
#pragma unroll
      for (int kk = 0; kk < 2; kk++)
        pa[i][kk] = *(const short8*)(Pb + (i * 16 + lr) * 144 + kk * 64 + lg * 16);
#pragma unroll
    for (int j = 0; j < 8; j++) {
      short8 bv[2];
#pragma unroll
      for (int kk = 0; kk < 2; kk++)
        bv[kk] = *(const short8*)&vbase[(j * 16 + lr) * 256 + ct * 64 + kk * 32 + lg * 8];
#pragma unroll
      for (int i = 0; i < 2; i++)
#pragma unroll
        for (int kk = 0; kk < 2; kk++)
          o_acc[i][j] = __builtin_amdgcn_mfma_f32_16x16x32_bf16(pa[i][kk], bv[kk], o_acc[i][j], 0, 0, 0);
    }
  }

  int nm = nmh >> 3, h = nmh & 7;
#pragma unroll
  for (int i = 0; i < 2; i++)
#pragma unroll
    for (int j = 0; j < 8; j++)
#pragma unroll
      for (int r = 0; r < 4; r++) {
        int t = w * 32 + i * 16 + lg * 4 + r;
        int d = h * 128 + j * 16 + lr;
        ao[((size_t)nm * 256 + t) * 1024 + d] = f2bf(o_acc[i][j][r] * rs[i][r]);
      }
}

extern "C" void kernel_launch(void* const* d_in, const int* in_sizes, int n_in,
                              void* d_out, int out_size, void* d_ws, size_t ws_size,
                              hipStream_t stream) {
  const float* x = (const float*)d_in[0];
  const float* ln_g = (const float*)d_in[1];
  const float* ln_b = (const float*)d_in[2];
  const float* w_qkv = (const float*)d_in[3];
  const float* w_out = (const float*)d_in[4];
  const float* b_out = (const float*)d_in[5];
  const float* w_lin = (const float*)d_in[6];
  const float* b_lin = (const float*)d_in[7];
  float* out = (float*)d_out;

  char* ws = (char*)d_ws;
  size_t off = 0;
  auto alloc = [&](size_t bytes) -> void* {
    void* p = ws + off;
    off = (off + bytes + 255) & ~(size_t)255;
    return p;
  };

  ushort* wqkvT = (ushort*)alloc((size_t)3072 * 960 * 2);
  ushort* woutT = (ushort*)alloc((size_t)1024 * 1024 * 2);
  ushort* whi   = (ushort*)alloc((size_t)65536 * 2);
  ushort* wlo   = (ushort*)alloc((size_t)65536 * 2);
  ushort* xn    = (ushort*)alloc((size_t)32768 * 960 * 2);
  ushort* qbuf  = (ushort*)alloc((size_t)1024 * 256 * 128 * 2);
  ushort* kbuf  = (ushort*)alloc((size_t)1024 * 256 * 128 * 2);
  ushort* vTbuf = (ushort*)alloc((size_t)1024 * 256 * 128 * 2);
  ushort* attnout = (ushort*)alloc((size_t)32768 * 1024 * 2);
  ushort* x2hi  = kbuf;   // [nm][960][256] bf16 (k region free after attn)
  ushort* x2lo  = vTbuf;  // (vT region free after attn)

  wtrans_kernel<<<dim3(96, 30), 256, 0, stream>>>(w_qkv, wqkvT, 960, 3072);
  wtrans_kernel<<<dim3(32, 32), 256, 0, stream>>>(w_out, woutT, 1024, 960);
  wsplit_kernel<<<dim3(256), 256, 0, stream>>>(w_lin, whi, wlo, 65536);

  ln_fused_kernel<<<dim3(8, 128), 512, 0, stream>>>(x, ln_g, ln_b, xn);

  gemm256<0><<<dim3(12, 128), 512, 0, stream>>>(xn, 960, wqkvT, 960, 15, nullptr, nullptr,
                                                qbuf, kbuf, vTbuf, nullptr, nullptr, nullptr);
  attn2_kernel<<<dim3(1024), 512, 0, stream>>>(qbuf, kbuf, vTbuf, attnout);
  gemm256<1><<<dim3(4, 128), 512, 0, stream>>>(attnout, 1024, woutT, 1024, 16, nullptr, nullptr,
                                               x2hi, x2lo, nullptr, b_out, x, nullptr);
  gemm256<2><<<dim3(1, 480), 512, 0, stream>>>(x2hi, 256, whi, 256, 12, x2lo, wlo,
                                               nullptr, nullptr, nullptr, b_lin, nullptr, out);
}

// Round 18
// 589.627 us; speedup vs baseline: 1.0503x; 1.0503x over previous
//
#include <hip/hip_runtime.h>

typedef unsigned short ushort;
using short8 = __attribute__((ext_vector_type(8))) short;
using f32x4  = __attribute__((ext_vector_type(4))) float;
using i32x4  = __attribute__((ext_vector_type(4))) int;
using us4    = __attribute__((ext_vector_type(4))) ushort;

static __device__ __forceinline__ float bf2f(ushort u) {
  union { unsigned int i; float f; } x; x.i = ((unsigned int)u) << 16; return x.f;
}
static __device__ __forceinline__ ushort f2bf(float f) {
  union { float f; unsigned int i; } x; x.f = f;
  unsigned int u = x.i;
  unsigned int r = u + 0x7fffu + ((u >> 16) & 1u);
  return (ushort)(r >> 16);
}

// async global -> LDS, 16B per lane; LDS dest is wave-uniform base + lane*16
#define GLOAD16(gp, lp)                                                   \
  __builtin_amdgcn_global_load_lds(                                      \
      (const __attribute__((address_space(1))) void*)(gp),               \
      (__attribute__((address_space(3))) void*)(lp), 16, 0, 0)

// ---------------- weight prep ----------------
__global__ __launch_bounds__(256) void wtrans_kernel(const float* __restrict__ in,
                                                     ushort* __restrict__ out,
                                                     int R, int C) {
  __shared__ float sl[32][33];
  int tx = threadIdx.x & 31, ty = threadIdx.x >> 5;
  int c0 = blockIdx.x * 32, r0 = blockIdx.y * 32;
#pragma unroll
  for (int s = 0; s < 4; s++) {
    int r = r0 + ty + s * 8;
    int c = c0 + tx;
    sl[ty + s * 8][tx] = (c < C) ? in[(size_t)r * C + c] : 0.f;
  }
  __syncthreads();
#pragma unroll
  for (int s = 0; s < 4; s++) {
    int c = c0 + ty + s * 8;
    int r = r0 + tx;
    out[(size_t)c * R + r] = f2bf(sl[tx][ty + s * 8]);
  }
}

__global__ void wsplit_kernel(const float* __restrict__ in, ushort* __restrict__ hi,
                              ushort* __restrict__ lo, int n) {
  int i = blockIdx.x * 256 + threadIdx.x;
  if (i < n) {
    float v = in[i];
    ushort h = f2bf(v);
    hi[i] = h;
    lo[i] = f2bf(v - bf2f(h));
  }
}

// ---------------- fused LayerNorm (R14-verified 32-t slab) ----------------
__global__ __launch_bounds__(512) void ln_fused_kernel(const float* __restrict__ x,
                                                       const float* __restrict__ g,
                                                       const float* __restrict__ b,
                                                       ushort* __restrict__ xn) {
  __shared__ float sl[960][34];
  __shared__ float smean[32], srstd[32];
  int tid = threadIdx.x;
  int nm = blockIdx.y;
  int t0 = blockIdx.x * 32;

  int r0 = tid >> 3, c4 = (tid & 7) * 4;
#pragma unroll
  for (int it = 0; it < 15; it++) {
    int r = it * 64 + r0;
    float4 v = *(const float4*)&x[((size_t)nm * 960 + r) * 256 + t0 + c4];
    *(float4*)&sl[r][c4] = v;
  }
  __syncthreads();

  int tg = tid >> 4, lt = tid & 15;
  float s = 0.f, ss = 0.f;
#pragma unroll 4
  for (int k = 0; k < 60; k++) {
    float v = sl[lt + k * 16][tg];
    s += v; ss += v * v;
  }
#pragma unroll
  for (int d = 1; d < 16; d <<= 1) {
    s += __shfl_xor(s, d, 64);
    ss += __shfl_xor(ss, d, 64);
  }
  if (lt == 0) {
    float mean = s * (1.f / 960.f);
    float var = ss * (1.f / 960.f) - mean * mean;
    smean[tg] = mean;
    srstd[tg] = rsqrtf(var + 1e-5f);
  }
  __syncthreads();

  float gg[2], bb[2];
#pragma unroll
  for (int c = 0; c < 2; c++) {
    int col = c * 512 + tid;
    if (col < 960) { gg[c] = g[col]; bb[c] = b[col]; }
  }
#pragma unroll
  for (int t = 0; t < 32; t++) {
    float mean = smean[t], rstd = srstd[t];
#pragma unroll
    for (int c = 0; c < 2; c++) {
      int col = c * 512 + tid;
      if (col < 960)
        xn[((size_t)nm * 256 + t0 + t) * 960 + col] =
            f2bf((sl[col][t] - mean) * rstd * gg[c] + bb[c]);
    }
  }
}

// ---------------- 256x256 GEMM, BK=64, 8 waves, counted-vmcnt pipeline (R9 anchor) ----
// LDS 128KB. Regions (16KB each, [256 rows][32 cols]): A(d,kk) @ d*32768+kk*16384,
// B(d,kk) @ 65536 + same. 16B-slot s stored at s ^ ((row>>1)&3) [verified 0-conflict].
// MODE 0: QKV epilogue.
// MODE 1: proj + b_out -> LDS bf16 tile -> coalesced residual(x) + hi/lo split.
// MODE 2: 3-seg split-bf16 + tanh -> f32 out.
template <int MODE>
__global__ __launch_bounds__(512, 2) void gemm256(
    const ushort* __restrict__ A, int lda, const ushort* __restrict__ BT, int ldb, int nkt,
    const ushort* __restrict__ Alo, const ushort* __restrict__ Blo,
    ushort* __restrict__ o0, ushort* __restrict__ o1, ushort* __restrict__ o2,
    const float* __restrict__ bias, const float* __restrict__ xres,
    float* __restrict__ fout) {
  __shared__ char smem[131072];
  int tid = threadIdx.x;
  int l = tid & 63, w = tid >> 6;
  int wr = w >> 2, wc = w & 3;
  int lr = l & 15, lg = l >> 4;
  int cb = blockIdx.x * 256, rb = blockIdx.y * 256;

  int srow = tid >> 2;
  int scol = ((tid & 3) ^ ((tid >> 3) & 3)) * 8;

  int swz = (lg ^ ((lr >> 1) & 3)) << 4;
  const char* ArdB = smem + (wr * 128 + lr) * 64 + swz;
  const char* BrdB = smem + 65536 + (wc * 64 + lr) * 64 + swz;

  auto stage_half = [&](int kt, int kk, int isB) {
    const ushort* P; int ld; int k0;
    if (MODE == 2) {
      int seg = kt >> 2; k0 = (kt & 3) * 64 + kk * 32;
      P = isB ? ((seg == 1) ? Blo : BT) : ((seg == 2) ? Alo : A);
      ld = 256;
    } else {
      P = isB ? BT : A; ld = isB ? ldb : lda; k0 = kt * 64 + kk * 32;
    }
    const ushort* gp = P + (size_t)((isB ? cb : rb) + srow) * ld + k0 + scol;
    char* dst = smem + isB * 65536 + (kt & 1) * 32768 + kk * 16384 + tid * 16;
    GLOAD16(gp, dst);
    GLOAD16(gp + (size_t)128 * ld, dst + 8192);
  };

  f32x4 acc[8][4];
#pragma unroll
  for (int i = 0; i < 8; i++)
#pragma unroll
    for (int j = 0; j < 4; j++) acc[i][j] = (f32x4){0.f, 0.f, 0.f, 0.f};

  stage_half(0, 0, 0); stage_half(0, 0, 1); stage_half(0, 1, 0); stage_half(0, 1, 1);
  asm volatile("s_waitcnt vmcnt(4)" ::: "memory");
  __builtin_amdgcn_s_barrier();

  for (int t = 0; t < nkt; t++) {
    const char* Ard = ArdB + (t & 1) * 32768;
    const char* Brd = BrdB + (t & 1) * 32768;
    bool st = (t + 1 < nkt);
    short8 a[4], b[4];

#pragma unroll
    for (int j = 0; j < 4; j++) b[j] = *(const short8*)(Brd + j * 1024);
#pragma unroll
    for (int i = 0; i < 4; i++) a[i] = *(const short8*)(Ard + i * 1024);
    if (st) stage_half(t + 1, 0, 0);
    __builtin_amdgcn_s_barrier();
    __builtin_amdgcn_s_setprio(1);
#pragma unroll
    for (int i = 0; i < 4; i++)
#pragma unroll
      for (int j = 0; j < 4; j++)
        acc[i][j] = __builtin_amdgcn_mfma_f32_16x16x32_bf16(a[i], b[j], acc[i][j], 0, 0, 0);
    __builtin_amdgcn_s_setprio(0);
    __builtin_amdgcn_s_barrier();

#pragma unroll
    for (int i = 0; i < 4; i++) a[i] = *(const short8*)(Ard + (4 + i) * 1024);
    if (st) stage_half(t + 1, 0, 1);
    __builtin_amdgcn_s_barrier();
    __builtin_amdgcn_s_setprio(1);
#pragma unroll
    for (int i = 0; i < 4; i++)
#pragma unroll
      for (int j = 0; j < 4; j++)
        acc[4 + i][j] = __builtin_amdgcn_mfma_f32_16x16x32_bf16(a[i], b[j], acc[4 + i][j], 0, 0, 0);
    __builtin_amdgcn_s_setprio(0);
    if (st) asm volatile("s_waitcnt vmcnt(4)" ::: "memory");
    else    asm volatile("s_waitcnt vmcnt(0)" ::: "memory");
    __builtin_amdgcn_s_barrier();

#pragma unroll
    for (int j = 0; j < 4; j++) b[j] = *(const short8*)(Brd + 16384 + j * 1024);
#pragma unroll
    for (int i = 0; i < 4; i++) a[i] = *(const short8*)(Ard + 16384 + i * 1024);
    if (st) stage_half(t + 1, 1, 0);
    __builtin_amdgcn_s_barrier();
    __builtin_amdgcn_s_setprio(1);
#pragma unroll
    for (int i = 0; i < 4; i++)
#pragma unroll
      for (int j = 0; j < 4; j++)
        acc[i][j] = __builtin_amdgcn_mfma_f32_16x16x32_bf16(a[i], b[j], acc[i][j], 0, 0, 0);
    __builtin_amdgcn_s_setprio(0);
    __builtin_amdgcn_s_barrier();

#pragma unroll
    for (int i = 0; i < 4; i++) a[i] = *(const short8*)(Ard + 16384 + (4 + i) * 1024);
    if (st) stage_half(t + 1, 1, 1);
    __builtin_amdgcn_s_barrier();
    __builtin_amdgcn_s_setprio(1);
#pragma unroll
    for (int i = 0; i < 4; i++)
#pragma unroll
      for (int j = 0; j < 4; j++)
        acc[4 + i][j] = __builtin_amdgcn_mfma_f32_16x16x32_bf16(a[i], b[j], acc[4 + i][j], 0, 0, 0);
    __builtin_amdgcn_s_setprio(0);
    if (st) asm volatile("s_waitcnt vmcnt(4)" ::: "memory");
    else    asm volatile("s_waitcnt vmcnt(0)" ::: "memory");
    __builtin_amdgcn_s_barrier();
  }

  int row0 = rb + wr * 128, col0 = cb + wc * 64;
  if (MODE == 0) {
    int nm = rb >> 8;
    int which = cb >> 10;
#pragma unroll
    for (int i = 0; i < 8; i++)
#pragma unroll
      for (int j = 0; j < 4; j++) {
        f32x4 v = acc[i][j];
        int col = col0 + j * 16 + lr;
        int cl = col & 1023;
        int h = cl >> 7, d = cl & 127;
        int nmh = nm * 8 + h;
        int t0 = wr * 128 + i * 16 + lg * 4;
        if (which == 2) {
          us4 pk;
          pk.x = f2bf(v[0]); pk.y = f2bf(v[1]); pk.z = f2bf(v[2]); pk.w = f2bf(v[3]);
          *(us4*)&o2[((size_t)nmh * 128 + d) * 256 + t0] = pk;  // V^T, 8B packed
        } else if (which == 0) {
#pragma unroll
          for (int r = 0; r < 4; r++)
            o0[((size_t)nmh * 256 + t0 + r) * 128 + d] = f2bf(v[r] * 0.08838834764831845f);
        } else {
#pragma unroll
          for (int r = 0; r < 4; r++)
            o1[((size_t)nmh * 256 + t0 + r) * 128 + d] = f2bf(v[r]);
        }
      }
  } else if (MODE == 1) {
    // stash proj+bias (bf16) into LDS [cv_local][t], swizzled slot (t*2)^((cv&15)<<3)
    int nm = rb >> 8;
#pragma unroll
    for (int i = 0; i < 8; i++)
#pragma unroll
      for (int j = 0; j < 4; j++) {
        f32x4 v = acc[i][j];
        int cvl = wc * 64 + j * 16 + lr;
        int col = cb + cvl;
        float bb = (col < 960) ? bias[col] : 0.f;
        int t0 = wr * 128 + i * 16 + lg * 4;
        us4 pk;
        pk.x = f2bf(v[0] + bb); pk.y = f2bf(v[1] + bb);
        pk.z = f2bf(v[2] + bb); pk.w = f2bf(v[3] + bb);
        *(us4*)(smem + cvl * 512 + ((t0 * 2) ^ ((cvl & 15) << 3))) = pk;
      }
    __syncthreads();
    // coalesced pass: wave w covers cv rows {it*8+w}; lane l covers t=4l..4l+3
    for (int it = 0; it < 32; it++) {
      int cvl = it * 8 + w;
      int col = cb + cvl;
      if (col < 960) {
        us4 pv = *(const us4*)(smem + cvl * 512 + ((l * 8) ^ ((cvl & 15) << 3)));
        size_t base = ((size_t)nm * 960 + col) * 256 + l * 4;
        f32x4 xv = *(const f32x4*)&xres[base];
        us4 h4, l4;
#pragma unroll
        for (int e = 0; e < 4; e++) {
          float s = xv[e] + bf2f(pv[e]);
          ushort hh = f2bf(s);
          h4[e] = hh;
          l4[e] = f2bf(s - bf2f(hh));
        }
        *(us4*)&o0[base] = h4;
        *(us4*)&o1[base] = l4;
      }
    }
  } else {
#pragma unroll
    for (int i = 0; i < 8; i++)
#pragma unroll
      for (int j = 0; j < 4; j++) {
        f32x4 v = acc[i][j];
        int col = col0 + j * 16 + lr;
        float bb = bias[col];
#pragma unroll
        for (int r = 0; r < 4; r++) {
          int row = row0 + i * 16 + lg * 4 + r;
          fout[(size_t)row * 256 + col] = tanhf(v[r] + bb);
        }
      }
  }
}

// ---------------- attention v2: one block per head, K/V staged once (verified best) ----
__global__ __launch_bounds__(512, 2) void attn2_kernel(const ushort* __restrict__ q,
                                                       const ushort* __restrict__ kb,
                                                       const ushort* __restrict__ vT,
                                                       ushort* __restrict__ ao) {
  __shared__ char smem[131072];
  int tid = threadIdx.x;
  int l = tid & 63, w = tid >> 6;
  int lr = l & 15, lg = l >> 4;
  int nmh = blockIdx.x;

  const ushort* kbase = kb + (size_t)nmh * 32768;
  const ushort* vbase = vT + (size_t)nmh * 32768;

#pragma unroll
  for (int u = 0; u < 8; u++) {
    int row = u * 32 + w * 4 + (l >> 4);
    int slot = l & 15;
    GLOAD16(kbase + row * 128 + ((slot ^ (row & 7)) * 8), smem + u * 8192 + w * 1024);
  }
  short8 aq[2][4];
  {
    const ushort* qp = q + (size_t)nmh * 32768 + (size_t)(w * 32 + lr) * 128 + lg * 8;
#pragma unroll
    for (int i = 0; i < 2; i++)
#pragma unroll
      for (int kk = 0; kk < 4; kk++) aq[i][kk] = *(const short8*)(qp + i * 2048 + kk * 32);
  }
#pragma unroll
  for (int u = 0; u < 8; u++) {
    int row = u * 16 + w * 2 + (l >> 5);
    int slot = l & 31;
    GLOAD16(vbase + row * 256 + ((slot ^ (row & 7)) * 8),
            smem + 65536 + u * 8192 + w * 1024);
  }
  asm volatile("s_waitcnt vmcnt(8)" ::: "memory");
  __builtin_amdgcn_s_barrier();

  f32x4 s_acc[2][16];
#pragma unroll
  for (int i = 0; i < 2; i++)
#pragma unroll
    for (int j = 0; j < 16; j++) s_acc[i][j] = (f32x4){0.f, 0.f, 0.f, 0.f};
#pragma unroll
  for (int j = 0; j < 16; j++) {
    short8 bk[4];
#pragma unroll
    for (int kk = 0; kk < 4; kk++)
      bk[kk] = *(const short8*)(smem + (j * 16 + lr) * 256 + (((kk * 4 + lg) ^ (lr & 7)) << 4));
#pragma unroll
    for (int i = 0; i < 2; i++)
#pragma unroll
      for (int kk = 0; kk < 4; kk++)
        s_acc[i][j] = __builtin_amdgcn_mfma_f32_16x16x32_bf16(aq[i][kk], bk[kk], s_acc[i][j], 0, 0, 0);
  }

  float m[2][4], sum[2][4], rs[2][4];
#pragma unroll
  for (int i = 0; i < 2; i++)
#pragma unroll
    for (int r = 0; r < 4; r++) m[i][r] = -1e30f;
#pragma unroll
  for (int i = 0; i < 2; i++)
#pragma unroll
    for (int j = 0; j < 16; j++)
#pragma unroll
      for (int r = 0; r < 4; r++) m[i][r] = fmaxf(m[i][r], s_acc[i][j][r]);
#pragma unroll
  for (int d = 1; d < 16; d <<= 1)
#pragma unroll
    for (int i = 0; i < 2; i++)
#pragma unroll
      for (int r = 0; r < 4; r++) m[i][r] = fmaxf(m[i][r], __shfl_xor(m[i][r], d, 64));
#pragma unroll
  for (int i = 0; i < 2; i++)
#pragma unroll
    for (int r = 0; r < 4; r++) sum[i][r] = 0.f;
#pragma unroll
  for (int i = 0; i < 2; i++)
#pragma unroll
    for (int j = 0; j < 16; j++)
#pragma unroll
      for (int r = 0; r < 4; r++) {
        float p = __expf(s_acc[i][j][r] - m[i][r]);
        s_acc[i][j][r] = p;
        sum[i][r] += p;
      }
#pragma unroll
  for (int d = 1; d < 16; d <<= 1)
#pragma unroll
    for (int i = 0; i < 2; i++)
#pragma unroll
      for (int r = 0; r < 4; r++) sum[i][r] += __shfl_xor(sum[i][r], d, 64);
#pragma unroll
  for (int i = 0; i < 2; i++)
#pragma unroll
    for (int r = 0; r < 4; r++) rs[i][r] = 1.f / sum[i][r];

  __builtin_amdgcn_s_barrier();
  asm volatile("s_waitcnt vmcnt(0)" ::: "memory");

  char* Pb = smem + w * 4608;
  f32x4 o_acc[2][8];
#pragma unroll
  for (int i = 0; i < 2; i++)
#pragma unroll
    for (int j = 0; j < 8; j++) o_acc[i][j] = (f32x4){0.f, 0.f, 0.f, 0.f};

#pragma unroll
  for (int ct = 0; ct < 4; ct++) {
#pragma unroll
    for (int i = 0; i < 2; i++)
#pragma unroll
      for (int jj = 0; jj < 4; jj++)
#pragma unroll
        for (int r = 0; r < 4; r++)
          *(ushort*)(Pb + (i * 16 + lg * 4 + r) * 144 + (jj * 16 + lr) * 2) =
              f2bf(s_acc[i][ct * 4 + jj][r]);
    short8 pa[2][2];
#pragma unroll
    for (int i = 0; i < 2; i++)
#pragma unroll
      for (int kk = 0; kk < 2; kk++)
        pa[i][kk] = *(const short8*)(Pb + (i * 16 + lr) * 144 + kk * 64 + lg * 16);
#pragma unroll
    for (int j = 0; j < 8; j++) {
      short8 bv[2];
#pragma unroll
      for (int kk = 0; kk < 2; kk++)
        bv[kk] = *(const short8*)(smem + 65536 + (j * 16 + lr) * 512 +
                                  (((ct * 8 + kk * 4 + lg) ^ (lr & 7)) << 4));
#pragma unroll
      for (int i = 0; i < 2; i++)
#pragma unroll
        for (int kk = 0; kk < 2; kk++)
          o_acc[i][j] = __builtin_amdgcn_mfma_f32_16x16x32_bf16(pa[i][kk], bv[kk], o_acc[i][j], 0, 0, 0);
    }
  }

  int nm = nmh >> 3, h = nmh & 7;
#pragma unroll
  for (int i = 0; i < 2; i++)
#pragma unroll
    for (int j = 0; j < 8; j++)
#pragma unroll
      for (int r = 0; r < 4; r++) {
        int t = w * 32 + i * 16 + lg * 4 + r;
        int d = h * 128 + j * 16 + lr;
        ao[((size_t)nm * 256 + t) * 1024 + d] = f2bf(o_acc[i][j][r] * rs[i][r]);
      }
}

extern "C" void kernel_launch(void* const* d_in, const int* in_sizes, int n_in,
                              void* d_out, int out_size, void* d_ws, size_t ws_size,
                              hipStream_t stream) {
  const float* x = (const float*)d_in[0];
  const float* ln_g = (const float*)d_in[1];
  const float* ln_b = (const float*)d_in[2];
  const float* w_qkv = (const float*)d_in[3];
  const float* w_out = (const float*)d_in[4];
  const float* b_out = (const float*)d_in[5];
  const float* w_lin = (const float*)d_in[6];
  const float* b_lin = (const float*)d_in[7];
  float* out = (float*)d_out;

  char* ws = (char*)d_ws;
  size_t off = 0;
  auto alloc = [&](size_t bytes) -> void* {
    void* p = ws + off;
    off = (off + bytes + 255) & ~(size_t)255;
    return p;
  };

  ushort* wqkvT = (ushort*)alloc((size_t)3072 * 960 * 2);
  ushort* woutT = (ushort*)alloc((size_t)1024 * 1024 * 2);
  ushort* whi   = (ushort*)alloc((size_t)65536 * 2);
  ushort* wlo   = (ushort*)alloc((size_t)65536 * 2);
  ushort* xn    = (ushort*)alloc((size_t)32768 * 960 * 2);
  ushort* qbuf  = (ushort*)alloc((size_t)1024 * 256 * 128 * 2);
  ushort* kbuf  = (ushort*)alloc((size_t)1024 * 256 * 128 * 2);
  ushort* vTbuf = (ushort*)alloc((size_t)1024 * 256 * 128 * 2);
  ushort* attnout = (ushort*)alloc((size_t)32768 * 1024 * 2);
  ushort* x2hi  = kbuf;   // [nm][960][256] bf16 (k region free after attn)
  ushort* x2lo  = vTbuf;  // (vT region free after attn)

  wtrans_kernel<<<dim3(96, 30), 256, 0, stream>>>(w_qkv, wqkvT, 960, 3072);
  wtrans_kernel<<<dim3(32, 32), 256, 0, stream>>>(w_out, woutT, 1024, 960);
  wsplit_kernel<<<dim3(256), 256, 0, stream>>>(w_lin, whi, wlo, 65536);

  ln_fused_kernel<<<dim3(8, 128), 512, 0, stream>>>(x, ln_g, ln_b, xn);

  gemm256<0><<<dim3(12, 128), 512, 0, stream>>>(xn, 960, wqkvT, 960, 15, nullptr, nullptr,
                                                qbuf, kbuf, vTbuf, nullptr, nullptr, nullptr);
  attn2_kernel<<<dim3(1024), 512, 0, stream>>>(qbuf, kbuf, vTbuf, attnout);
  gemm256<1><<<dim3(4, 128), 512, 0, stream>>>(attnout, 1024, woutT, 1024, 16, nullptr, nullptr,
                                               x2hi, x2lo, nullptr, b_out, x, nullptr);
  gemm256<2><<<dim3(1, 480), 512, 0, stream>>>(x2hi, 256, whi, 256, 12, x2lo, wlo,
                                               nullptr, nullptr, nullptr, b_lin, nullptr, out);
}